// Round 4
// baseline (532.462 us; speedup 1.0000x reference)
//
#include <hip/hip_runtime.h>

// SIRcell: B=4, N=5000, mob (B,N,N) f32 = 400 MB — memory-bound, mob read ONCE.
// One pass computes BOTH einsums:
//   rowsum[b,i] = sum_j mob[b,i,j] * Iv[b,j]
//   colsum[b,j] = sum_i mob[b,i,j] * (Iv[b,i]/pop[b,i])
// Phase 1: grid (P partials × B), P=256 (or 250 fallback). Block k handles
// rows i ≡ k (mod P). Threads own fixed float4 column slices -> colsum
// partials in REGISTERS (no atomics). Round-4 changes:
//  - explicit register double-buffer: next row's 5 loads + SIR scalars issued
//    BEFORE processing current row (guaranteed latency overlap)
//  - rowsum reduction DEFERRED: 1 ds_write per row into red[r][t]; single
//    reduction pass at the end (removes 6 serial shuffles from the hot loop)
// Phase 2: reduce P column partials + epilogue + float4 store of (B,N,4).

constexpr int B    = 4;
constexpr int N    = 5000;
constexpr int NT   = 256;   // phase-1 threads/block
constexpr int ROWS = 20;    // max rows/block; requires P >= 250

typedef float f32x4 __attribute__((ext_vector_type(4)));

__global__ __launch_bounds__(NT, 4) void sir_phase1(
    const float* __restrict__ mob, const float* __restrict__ SIR,
    float* __restrict__ ws_row, float* __restrict__ ws_col, int P)
{
    const int b = blockIdx.y;
    const int k = blockIdx.x;          // partial index; rows i = k + P*r
    const int t = threadIdx.x;

    __shared__ float red[ROWS][NT];    // per-(row,thread) rowsum partials (20 KB)

    const float* sir_b = SIR + (size_t)b * N * 3;
    const float* mob_b = mob + (size_t)b * N * N;

    // Iv for owned columns (Iv[j] = SIR[b,j,1], stride-3) -> registers
    f32x4 iv[5];
    #pragma unroll
    for (int kk = 0; kk < 5; ++kk) {
        const int j4 = 4 * t + 1024 * kk;
        if (kk < 4 || t < 226) {
            iv[kk][0] = sir_b[(j4 + 0) * 3 + 1];
            iv[kk][1] = sir_b[(j4 + 1) * 3 + 1];
            iv[kk][2] = sir_b[(j4 + 2) * 3 + 1];
            iv[kk][3] = sir_b[(j4 + 3) * 3 + 1];
        } else {
            iv[kk] = (f32x4)0.f;
        }
    }

    f32x4 col[5];
    #pragma unroll
    for (int kk = 0; kk < 5; ++kk) col[kk] = (f32x4)0.f;

    f32x4 mc[5], mn[5];

    // prologue: load row k + its SIR scalars
    {
        const float* mrow = mob_b + (size_t)k * N;
        #pragma unroll
        for (int kk = 0; kk < 4; ++kk)
            mc[kk] = __builtin_nontemporal_load(
                reinterpret_cast<const f32x4*>(mrow + 4 * t + 1024 * kk));
        mc[4] = (t < 226)
            ? __builtin_nontemporal_load(reinterpret_cast<const f32x4*>(mrow + 4 * t + 4096))
            : (f32x4)0.f;
    }
    float sc = sir_b[k * 3 + 0], ic = sir_b[k * 3 + 1], rc = sir_b[k * 3 + 2];

    int r = 0;
    for (int i = k; i < N; i += P, ++r) {
        const int inext = i + P;
        float sn = 0.f, in_ = 0.f, rn = 0.f;
        if (inext < N) {
            // prefetch next row into mn + next SIR scalars (overlaps FMAs below)
            const float* mrow = mob_b + (size_t)inext * N;
            #pragma unroll
            for (int kk = 0; kk < 4; ++kk)
                mn[kk] = __builtin_nontemporal_load(
                    reinterpret_cast<const f32x4*>(mrow + 4 * t + 1024 * kk));
            mn[4] = (t < 226)
                ? __builtin_nontemporal_load(reinterpret_cast<const f32x4*>(mrow + 4 * t + 4096))
                : (f32x4)0.f;
            sn = sir_b[inext * 3 + 0];
            in_ = sir_b[inext * 3 + 1];
            rn = sir_b[inext * 3 + 2];
        }

        const float w = ic / (sc + ic + rc);   // Iv[i]/pop[i]
        float rp = 0.f;
        #pragma unroll
        for (int kk = 0; kk < 5; ++kk) {
            rp = fmaf(mc[kk][0], iv[kk][0], rp);
            rp = fmaf(mc[kk][1], iv[kk][1], rp);
            rp = fmaf(mc[kk][2], iv[kk][2], rp);
            rp = fmaf(mc[kk][3], iv[kk][3], rp);
            col[kk][0] = fmaf(mc[kk][0], w, col[kk][0]);
            col[kk][1] = fmaf(mc[kk][1], w, col[kk][1]);
            col[kk][2] = fmaf(mc[kk][2], w, col[kk][2]);
            col[kk][3] = fmaf(mc[kk][3], w, col[kk][3]);
        }
        red[r][t] = rp;                        // deferred reduction

        #pragma unroll
        for (int kk = 0; kk < 5; ++kk) mc[kk] = mn[kk];
        sc = sn; ic = in_; rc = rn;
    }
    __syncthreads();

    // end reduction: wave w handles rows r = w, w+4, ...
    const int wave = t >> 6, lane = t & 63;
    for (int q = wave; q < r; q += 4) {
        float v = red[q][lane] + red[q][lane + 64] + red[q][lane + 128] + red[q][lane + 192];
        #pragma unroll
        for (int off = 32; off > 0; off >>= 1)
            v += __shfl_xor(v, off, 64);
        if (lane == 0) ws_row[(size_t)b * N + k + P * q] = v;
    }

    // column partials (coalesced float4, single-use -> nontemporal)
    float* cp = ws_col + ((size_t)b * P + k) * N;
    #pragma unroll
    for (int kk = 0; kk < 4; ++kk)
        __builtin_nontemporal_store(col[kk],
            reinterpret_cast<f32x4*>(cp + 4 * t + 1024 * kk));
    if (t < 226)
        __builtin_nontemporal_store(col[4],
            reinterpret_cast<f32x4*>(cp + 4 * t + 4096));
}

__global__ __launch_bounds__(256) void sir_phase2(
    const float* __restrict__ ws_row, const float* __restrict__ ws_col,
    const float* __restrict__ SIR, const float* __restrict__ pb,
    const float* __restrict__ pg, float* __restrict__ out, int P)
{
    const int b = blockIdx.y;
    const int j = blockIdx.x * 256 + threadIdx.x;
    if (j >= N) return;

    const float* base = ws_col + (size_t)b * P * N + j;
    float cs = 0.f;
    #pragma unroll 8
    for (int p = 0; p < P; ++p)
        cs += __builtin_nontemporal_load(base + (size_t)p * N);

    const float s  = SIR[((size_t)b * N + j) * 3 + 0];
    const float ii = SIR[((size_t)b * N + j) * 3 + 1];
    const float rr = SIR[((size_t)b * N + j) * 3 + 2];
    const float pop = s + ii + rr;
    const float tr = ws_row[(size_t)b * N + j] / pop;   // term_row
    const float inew = pb[b] * (cs + tr);               // param_b * propagation
    const float ig = ii * pg[b];

    f32x4 o;
    o[0] = inew;            // I_new
    o[1] = s - inew;        // S_t
    o[2] = ii + inew - ig;  // I_t
    o[3] = ig + rr;         // R_t
    *reinterpret_cast<f32x4*>(out + ((size_t)b * N + j) * 4) = o;
}

extern "C" void kernel_launch(void* const* d_in, const int* in_sizes, int n_in,
                              void* d_out, int out_size, void* d_ws, size_t ws_size,
                              hipStream_t stream)
{
    const float* pb  = (const float*)d_in[0];
    const float* pg  = (const float*)d_in[1];
    const float* mob = (const float*)d_in[2];
    const float* SIR = (const float*)d_in[3];
    float* out = (float*)d_out;
    float* ws  = (float*)d_ws;

    // P partials per batch; needs (B*N + B*P*N)*4 bytes of ws (≈20.6 MB at 256)
    int P = 256;
    if (((size_t)B * N + (size_t)B * P * N) * 4 > ws_size) P = 250;  // ROWS=20 still holds

    float* ws_row = ws;            // B*N floats
    float* ws_col = ws + B * N;    // B*P*N floats

    sir_phase1<<<dim3(P, B), NT, 0, stream>>>(mob, SIR, ws_row, ws_col, P);
    sir_phase2<<<dim3((N + 255) / 256, B), 256, 0, stream>>>(
        ws_row, ws_col, SIR, pb, pg, out, P);
}

// Round 5
// 528.221 us; speedup vs baseline: 1.0080x; 1.0080x over previous
//
#include <hip/hip_runtime.h>

// SIRcell: B=4, N=5000, mob (B,N,N) f32 = 400 MB — memory-bound, mob read ONCE.
// One pass computes BOTH einsums:
//   rowsum[b,i] = sum_j mob[b,i,j] * Iv[b,j]
//   colsum[b,j] = sum_i mob[b,i,j] * (Iv[b,i]/pop[b,i])
// Round-5 change: CONTIGUOUS row blocks. Block k owns rows [20k, 20k+20) so it
// streams a contiguous 400 KB region (DRAM page locality — the strided-mod-P
// scheme jumped 5.12 MB between 20 KB rows and sat at ~3.2 TB/s). Per-row SIR
// scalars precomputed into LDS wv[20] (no serial scalar loads in the hot loop).
// Threads own fixed float4 column slices -> colsum partials in REGISTERS.
// Rowsum: 1 ds_write per row, reduced once at the end.
// Phase 2: reduce P column partials + epilogue + float4 store of (B,N,4).

constexpr int B   = 4;
constexpr int N   = 5000;
constexpr int NT  = 256;   // phase-1 threads/block
constexpr int RPB = 20;    // contiguous rows per block
constexpr int P   = 250;   // blocks per batch = N/RPB

typedef float f32x4 __attribute__((ext_vector_type(4)));

__global__ __launch_bounds__(NT, 4) void sir_phase1(
    const float* __restrict__ mob, const float* __restrict__ SIR,
    float* __restrict__ ws_row, float* __restrict__ ws_col)
{
    const int b  = blockIdx.y;
    const int k  = blockIdx.x;
    const int k0 = k * RPB;            // first row of this block
    const int t  = threadIdx.x;

    __shared__ float red[RPB][NT];     // per-(row,thread) rowsum partials (20 KB)
    __shared__ float wv[RPB];          // Iv[i]/pop[i] per row

    const float* sir_b = SIR + (size_t)b * N * 3;
    const float* mob_b = mob + (size_t)b * N * N;

    // Iv for owned columns (Iv[j] = SIR[b,j,1], stride-3) -> registers
    f32x4 iv[5];
    #pragma unroll
    for (int kk = 0; kk < 5; ++kk) {
        const int j4 = 4 * t + 1024 * kk;
        if (kk < 4 || t < 226) {
            iv[kk][0] = sir_b[(j4 + 0) * 3 + 1];
            iv[kk][1] = sir_b[(j4 + 1) * 3 + 1];
            iv[kk][2] = sir_b[(j4 + 2) * 3 + 1];
            iv[kk][3] = sir_b[(j4 + 3) * 3 + 1];
        } else {
            iv[kk] = (f32x4)0.f;
        }
    }

    // per-row weights w = I/(S+I+R) for the block's 20 rows
    if (t < RPB) {
        const int i = k0 + t;
        const float s  = sir_b[i * 3 + 0];
        const float ii = sir_b[i * 3 + 1];
        const float rr = sir_b[i * 3 + 2];
        wv[t] = ii / (s + ii + rr);
    }

    f32x4 col[5];
    #pragma unroll
    for (int kk = 0; kk < 5; ++kk) col[kk] = (f32x4)0.f;

    f32x4 mc[5], mn[5];

    // prologue: load first row
    {
        const float* mrow = mob_b + (size_t)k0 * N;
        #pragma unroll
        for (int kk = 0; kk < 4; ++kk)
            mc[kk] = __builtin_nontemporal_load(
                reinterpret_cast<const f32x4*>(mrow + 4 * t + 1024 * kk));
        mc[4] = (t < 226)
            ? __builtin_nontemporal_load(reinterpret_cast<const f32x4*>(mrow + 4 * t + 4096))
            : (f32x4)0.f;
    }
    __syncthreads();   // wv ready

    for (int r = 0; r < RPB; ++r) {
        if (r + 1 < RPB) {
            // prefetch next (adjacent) row — overlaps the FMAs below
            const float* mrow = mob_b + (size_t)(k0 + r + 1) * N;
            #pragma unroll
            for (int kk = 0; kk < 4; ++kk)
                mn[kk] = __builtin_nontemporal_load(
                    reinterpret_cast<const f32x4*>(mrow + 4 * t + 1024 * kk));
            mn[4] = (t < 226)
                ? __builtin_nontemporal_load(reinterpret_cast<const f32x4*>(mrow + 4 * t + 4096))
                : (f32x4)0.f;
        }

        const float w = wv[r];
        float rp = 0.f;
        #pragma unroll
        for (int kk = 0; kk < 5; ++kk) {
            rp = fmaf(mc[kk][0], iv[kk][0], rp);
            rp = fmaf(mc[kk][1], iv[kk][1], rp);
            rp = fmaf(mc[kk][2], iv[kk][2], rp);
            rp = fmaf(mc[kk][3], iv[kk][3], rp);
            col[kk][0] = fmaf(mc[kk][0], w, col[kk][0]);
            col[kk][1] = fmaf(mc[kk][1], w, col[kk][1]);
            col[kk][2] = fmaf(mc[kk][2], w, col[kk][2]);
            col[kk][3] = fmaf(mc[kk][3], w, col[kk][3]);
        }
        red[r][t] = rp;                // deferred rowsum reduction

        #pragma unroll
        for (int kk = 0; kk < 5; ++kk) mc[kk] = mn[kk];
    }
    __syncthreads();

    // end reduction: wave w handles rows q = w, w+4, ...
    const int wave = t >> 6, lane = t & 63;
    for (int q = wave; q < RPB; q += 4) {
        float v = red[q][lane] + red[q][lane + 64] + red[q][lane + 128] + red[q][lane + 192];
        #pragma unroll
        for (int off = 32; off > 0; off >>= 1)
            v += __shfl_xor(v, off, 64);
        if (lane == 0) ws_row[(size_t)b * N + k0 + q] = v;
    }

    // column partials (coalesced float4, single-use -> nontemporal)
    float* cp = ws_col + ((size_t)b * P + k) * N;
    #pragma unroll
    for (int kk = 0; kk < 4; ++kk)
        __builtin_nontemporal_store(col[kk],
            reinterpret_cast<f32x4*>(cp + 4 * t + 1024 * kk));
    if (t < 226)
        __builtin_nontemporal_store(col[4],
            reinterpret_cast<f32x4*>(cp + 4 * t + 4096));
}

__global__ __launch_bounds__(256) void sir_phase2(
    const float* __restrict__ ws_row, const float* __restrict__ ws_col,
    const float* __restrict__ SIR, const float* __restrict__ pb,
    const float* __restrict__ pg, float* __restrict__ out)
{
    const int b = blockIdx.y;
    const int j = blockIdx.x * 256 + threadIdx.x;
    if (j >= N) return;

    const float* base = ws_col + (size_t)b * P * N + j;
    float cs = 0.f;
    #pragma unroll 5
    for (int p = 0; p < P; ++p)
        cs += __builtin_nontemporal_load(base + (size_t)p * N);

    const float s  = SIR[((size_t)b * N + j) * 3 + 0];
    const float ii = SIR[((size_t)b * N + j) * 3 + 1];
    const float rr = SIR[((size_t)b * N + j) * 3 + 2];
    const float pop = s + ii + rr;
    const float tr = ws_row[(size_t)b * N + j] / pop;   // term_row
    const float inew = pb[b] * (cs + tr);               // param_b * propagation
    const float ig = ii * pg[b];

    f32x4 o;
    o[0] = inew;            // I_new
    o[1] = s - inew;        // S_t
    o[2] = ii + inew - ig;  // I_t
    o[3] = ig + rr;         // R_t
    *reinterpret_cast<f32x4*>(out + ((size_t)b * N + j) * 4) = o;
}

extern "C" void kernel_launch(void* const* d_in, const int* in_sizes, int n_in,
                              void* d_out, int out_size, void* d_ws, size_t ws_size,
                              hipStream_t stream)
{
    const float* pb  = (const float*)d_in[0];
    const float* pg  = (const float*)d_in[1];
    const float* mob = (const float*)d_in[2];
    const float* SIR = (const float*)d_in[3];
    float* out = (float*)d_out;
    float* ws  = (float*)d_ws;

    // needs (B*N + B*P*N)*4 B ≈ 20.1 MB of workspace (harness provides much more)
    float* ws_row = ws;            // B*N floats
    float* ws_col = ws + B * N;    // B*P*N floats

    sir_phase1<<<dim3(P, B), NT, 0, stream>>>(mob, SIR, ws_row, ws_col);
    sir_phase2<<<dim3((N + 255) / 256, B), 256, 0, stream>>>(
        ws_row, ws_col, SIR, pb, pg, out);
}